// Round 1
// baseline (607.919 us; speedup 1.0000x reference)
//
#include <hip/hip_runtime.h>
#include <hip/hip_bf16.h>
#include <float.h>

#define N 4096
#define DF 256

// ---------------- zero accumulators ----------------
__global__ __launch_bounds__(64) void zero_acc_kernel(float* acc) {
    if (threadIdx.x < 16) acc[threadIdx.x] = 0.f;
}

// ---------------- row squared norms ----------------
__global__ __launch_bounds__(256) void x2_kernel(const float* __restrict__ X,
                                                 float* __restrict__ x2) {
    __shared__ float red[256];
    int row = blockIdx.x;
    float v = X[row * DF + threadIdx.x];
    red[threadIdx.x] = v * v;
    __syncthreads();
    for (int s = 128; s > 0; s >>= 1) {
        if (threadIdx.x < s) red[threadIdx.x] += red[threadIdx.x + s];
        __syncthreads();
    }
    if (threadIdx.x == 0) x2[row] = red[0];
}

// ---------------- per-row 3-NN among same-class ----------------
__global__ __launch_bounds__(256) void knn_kernel(const float* __restrict__ X,
                                                  const int* __restrict__ labels,
                                                  const float* __restrict__ x2,
                                                  int* __restrict__ tn,
                                                  float* __restrict__ radii,
                                                  float* __restrict__ acc) {
    int i = blockIdx.x;
    int t = threadIdx.x;
    __shared__ float4 xi4[DF / 4];
    ((float*)xi4)[t] = X[i * DF + t];
    __syncthreads();
    int myl = labels[i];
    float x2i = x2[i];
    float b0 = FLT_MAX, b1 = FLT_MAX, b2 = FLT_MAX;
    int i0 = 0, i1 = 0, i2 = 0;
    for (int j = t; j < N; j += 256) {
        if (j == i) continue;
        if (labels[j] != myl) continue;
        const float4* xr = (const float4*)(X + j * DF);
        float dot = 0.f;
#pragma unroll 8
        for (int d = 0; d < DF / 4; ++d) {
            float4 a = xr[d];
            float4 b = xi4[d];
            dot += a.x * b.x + a.y * b.y + a.z * b.z + a.w * b.w;
        }
        float dd = fmaxf(x2i + x2[j] - 2.f * dot, 0.f);
        if (dd < b2) {
            if (dd < b1) {
                b2 = b1; i2 = i1;
                if (dd < b0) { b1 = b0; i1 = i0; b0 = dd; i0 = j; }
                else { b1 = dd; i1 = j; }
            } else { b2 = dd; i2 = j; }
        }
    }
    __shared__ float sb[256][3];
    __shared__ int   si[256][3];
    sb[t][0] = b0; sb[t][1] = b1; sb[t][2] = b2;
    si[t][0] = i0; si[t][1] = i1; si[t][2] = i2;
    __syncthreads();
    for (int s = 128; s > 0; s >>= 1) {
        if (t < s) {
            float A[3] = { sb[t][0], sb[t][1], sb[t][2] };
            int  AI[3] = { si[t][0], si[t][1], si[t][2] };
            float B[3] = { sb[t + s][0], sb[t + s][1], sb[t + s][2] };
            int  BI[3] = { si[t + s][0], si[t + s][1], si[t + s][2] };
            float m[3]; int mi[3];
            int p = 0, q = 0;
            for (int k = 0; k < 3; ++k) {
                if (A[p] <= B[q]) { m[k] = A[p]; mi[k] = AI[p]; ++p; }
                else { m[k] = B[q]; mi[k] = BI[q]; ++q; }
            }
            sb[t][0] = m[0]; sb[t][1] = m[1]; sb[t][2] = m[2];
            si[t][0] = mi[0]; si[t][1] = mi[1]; si[t][2] = mi[2];
        }
        __syncthreads();
    }
    if (t == 0) {
        tn[i * 3 + 0] = si[0][0];
        tn[i * 3 + 1] = si[0][1];
        tn[i * 3 + 2] = si[0][2];
        radii[i] = 1.f + sb[0][2];
        atomicAdd(&acc[0], sb[0][0] + sb[0][1] + sb[0][2]);
    }
}

// ---------------- sort radii (bitonic) + suffix sums ----------------
__global__ __launch_bounds__(1024) void sort_scan_kernel(const float* __restrict__ radii,
                                                         float* __restrict__ sorted_r,
                                                         float* __restrict__ ssum) {
    __shared__ float s[N];
    __shared__ float aux[1024];
    int t = threadIdx.x;
    for (int i = t; i < N; i += 1024) s[i] = radii[i];
    __syncthreads();
    for (int k = 2; k <= N; k <<= 1) {
        for (int j = k >> 1; j > 0; j >>= 1) {
            for (int i = t; i < N; i += 1024) {
                int ixj = i ^ j;
                if (ixj > i) {
                    bool up = ((i & k) == 0);
                    float a = s[i], b = s[ixj];
                    if ((a > b) == up) { s[i] = b; s[ixj] = a; }
                }
            }
            __syncthreads();
        }
    }
    float v0 = s[4 * t + 0], v1 = s[4 * t + 1], v2 = s[4 * t + 2], v3 = s[4 * t + 3];
    float tot = v0 + v1 + v2 + v3;
    aux[t] = tot;
    __syncthreads();
    // Hillis-Steele inclusive suffix scan over aux
    for (int off = 1; off < 1024; off <<= 1) {
        float add = (t + off < 1024) ? aux[t + off] : 0.f;
        __syncthreads();
        aux[t] += add;
        __syncthreads();
    }
    float suf_next = aux[t] - tot;        // sum of chunks strictly after t
    float s3 = v3 + suf_next;
    float s2 = v2 + s3;
    float s1 = v1 + s2;
    float s0 = v0 + s1;
    ssum[4 * t + 0] = s0;
    ssum[4 * t + 1] = s1;
    ssum[4 * t + 2] = s2;
    ssum[4 * t + 3] = s3;
    sorted_r[4 * t + 0] = v0;
    sorted_r[4 * t + 1] = v1;
    sorted_r[4 * t + 2] = v2;
    sorted_r[4 * t + 3] = v3;
    if (t == 0) ssum[N] = 0.f;
}

// ---------------- fused distance GEMM + push epilogue ----------------
#define BK 16
__global__ __launch_bounds__(256) void push_gemm_kernel(const float* __restrict__ X,
                                                        const float* __restrict__ x2,
                                                        const int* __restrict__ tn,
                                                        const float* __restrict__ sorted_r,
                                                        const float* __restrict__ ssum,
                                                        float* __restrict__ acc) {
    __shared__ float As[BK][68];
    __shared__ float Bs[BK][68];
    __shared__ float rs[N];
    __shared__ float ss[N + 1];
    __shared__ float red[256];
    int tx = threadIdx.x, ty = threadIdx.y;
    int tid = ty * 16 + tx;
    for (int k = tid; k < N; k += 256) rs[k] = sorted_r[k];
    for (int k = tid; k < N + 1; k += 256) ss[k] = ssum[k];

    int rowBase = blockIdx.y * 64, colBase = blockIdx.x * 64;
    float acc4[4][4];
#pragma unroll
    for (int i = 0; i < 4; ++i)
#pragma unroll
        for (int j = 0; j < 4; ++j) acc4[i][j] = 0.f;

    int lr = tid >> 2;   // 0..63
    int lc4 = tid & 3;   // 0..3
    const float4* Arow = (const float4*)(X + (size_t)(rowBase + lr) * DF);
    const float4* Brow = (const float4*)(X + (size_t)(colBase + lr) * DF);

    for (int k0 = 0; k0 < DF; k0 += BK) {
        float4 av = Arow[(k0 >> 2) + lc4];
        float4 bv = Brow[(k0 >> 2) + lc4];
        __syncthreads();
        As[lc4 * 4 + 0][lr] = av.x; As[lc4 * 4 + 1][lr] = av.y;
        As[lc4 * 4 + 2][lr] = av.z; As[lc4 * 4 + 3][lr] = av.w;
        Bs[lc4 * 4 + 0][lr] = bv.x; Bs[lc4 * 4 + 1][lr] = bv.y;
        Bs[lc4 * 4 + 2][lr] = bv.z; Bs[lc4 * 4 + 3][lr] = bv.w;
        __syncthreads();
#pragma unroll
        for (int kk = 0; kk < BK; ++kk) {
            float a[4], b[4];
#pragma unroll
            for (int i = 0; i < 4; ++i) a[i] = As[kk][ty * 4 + i];
#pragma unroll
            for (int j = 0; j < 4; ++j) b[j] = Bs[kk][tx * 4 + j];
#pragma unroll
            for (int i = 0; i < 4; ++i)
#pragma unroll
                for (int j = 0; j < 4; ++j) acc4[i][j] += a[i] * b[j];
        }
    }
    __syncthreads();
    float rmax = rs[N - 1];
    float local = 0.f;
#pragma unroll
    for (int i = 0; i < 4; ++i) {
        int row = rowBase + ty * 4 + i;
        float x2r = x2[row];
        int t0 = tn[row * 3 + 0], t1 = tn[row * 3 + 1], t2 = tn[row * 3 + 2];
#pragma unroll
        for (int j = 0; j < 4; ++j) {
            int col = colBase + tx * 4 + j;
            if (col == row || col == t0 || col == t1 || col == t2) continue;
            float d = fmaxf(x2r + x2[col] - 2.f * acc4[i][j], 0.f);
            if (d < rmax) {
                int lo = 0, hi = N;
                while (lo < hi) {
                    int mid = (lo + hi) >> 1;
                    if (rs[mid] <= d) lo = mid + 1; else hi = mid;
                }
                local += ss[lo] - d * (float)(N - lo);
            }
        }
    }
    red[tid] = local;
    __syncthreads();
    for (int s = 128; s > 0; s >>= 1) {
        if (tid < s) red[tid] += red[tid + s];
        __syncthreads();
    }
    if (tid == 0) atomicAdd(&acc[1], red[0]);
}

// ---------------- finalize ----------------
__global__ void finalize_kernel(const float* __restrict__ acc, float* __restrict__ out) {
    out[0] = (acc[0] + acc[1]) * (1.f / (float)N);
}

extern "C" void kernel_launch(void* const* d_in, const int* in_sizes, int n_in,
                              void* d_out, int out_size, void* d_ws, size_t ws_size,
                              hipStream_t stream) {
    const float* X = (const float*)d_in[0];
    const int* labels = (const int*)d_in[1];
    float* out = (float*)d_out;

    float* wsf    = (float*)d_ws;
    float* acc    = wsf;                 // [0]=pull, [1]=push
    float* x2     = wsf + 16;            // N
    float* radii  = x2 + N;              // N
    float* sorted = radii + N;           // N
    float* ssum   = sorted + N;          // N+1
    int*   tn     = (int*)(ssum + N + 15); // 3N ints

    hipLaunchKernelGGL(zero_acc_kernel, dim3(1), dim3(64), 0, stream, acc);
    hipLaunchKernelGGL(x2_kernel, dim3(N), dim3(256), 0, stream, X, x2);
    hipLaunchKernelGGL(knn_kernel, dim3(N), dim3(256), 0, stream, X, labels, x2, tn, radii, acc);
    hipLaunchKernelGGL(sort_scan_kernel, dim3(1), dim3(1024), 0, stream, radii, sorted, ssum);
    hipLaunchKernelGGL(push_gemm_kernel, dim3(N / 64, N / 64), dim3(16, 16), 0, stream,
                       X, x2, tn, sorted, ssum, acc);
    hipLaunchKernelGGL(finalize_kernel, dim3(1), dim3(1), 0, stream, acc, out);
}

// Round 2
// 292.636 us; speedup vs baseline: 2.0774x; 2.0774x over previous
//
#include <hip/hip_runtime.h>
#include <hip/hip_bf16.h>
#include <float.h>

#define N 4096
#define DF 256
#define NBINS 1024
#define MAXM 256

typedef __attribute__((ext_vector_type(8))) short short8v;
typedef __attribute__((ext_vector_type(8))) unsigned short ushort8v;
typedef __attribute__((ext_vector_type(4))) float floatx4;

__device__ inline unsigned short f2bf(float f) {
    __hip_bfloat16 h = __float2bfloat16(f);
    return *reinterpret_cast<unsigned short*>(&h);
}

// ---------------- zero accumulators ----------------
__global__ __launch_bounds__(64) void zero_acc_kernel(double* accd) {
    if (threadIdx.x < 8) accd[threadIdx.x] = 0.0;
}

// ---------------- row squared norms: 4 rows/block, wave per row ----------------
__global__ __launch_bounds__(256) void x2_kernel(const float* __restrict__ X,
                                                 float* __restrict__ x2) {
    int row = blockIdx.x * 4 + (threadIdx.x >> 6);
    int l = threadIdx.x & 63;
    float4 v = ((const float4*)(X + (size_t)row * DF))[l];
    float s = v.x * v.x + v.y * v.y + v.z * v.z + v.w * v.w;
#pragma unroll
    for (int off = 32; off > 0; off >>= 1) s += __shfl_xor(s, off, 64);
    if (l == 0) x2[row] = s;
}

// ---------------- class bucketing ----------------
__global__ __launch_bounds__(1024) void bucket_kernel(const int* __restrict__ labels,
                                                      int* __restrict__ cnt,
                                                      int* __restrict__ members) {
    __shared__ int scnt[64];
    int t = threadIdx.x;
    if (t < 64) scnt[t] = 0;
    __syncthreads();
    for (int i = t; i < N; i += 1024) {
        int c = labels[i];
        int pos = atomicAdd(&scnt[c], 1);
        if (pos < MAXM) members[(c << 8) + pos] = i;
    }
    __syncthreads();
    if (t < 64) cnt[t] = min(scnt[t], MAXM);
}

// ---------------- per-row 3-NN among same-class (1 wave / row) ----------------
__global__ __launch_bounds__(64) void knn_kernel(const float* __restrict__ X,
                                                 const int* __restrict__ labels,
                                                 const float* __restrict__ x2,
                                                 const int* __restrict__ cnt,
                                                 const int* __restrict__ members,
                                                 float* __restrict__ radii,
                                                 float* __restrict__ targetd,
                                                 double* __restrict__ accd) {
    int i = blockIdx.x;
    int t = threadIdx.x;
    __shared__ float4 xi4[DF / 4];
    xi4[t] = ((const float4*)(X + (size_t)i * DF))[t];
    __syncthreads();
    int c = labels[i];
    int m = cnt[c];
    const int* mem = members + (c << 8);
    float x2i = x2[i];
    float b0 = FLT_MAX, b1 = FLT_MAX, b2 = FLT_MAX;
    for (int idx = t; idx < m; idx += 64) {
        int j = mem[idx];
        if (j == i) continue;
        const float4* xr = (const float4*)(X + (size_t)j * DF);
        float dot = 0.f;
#pragma unroll 8
        for (int d = 0; d < DF / 4; ++d) {
            float4 a = xr[d];
            float4 b = xi4[d];
            dot += a.x * b.x + a.y * b.y + a.z * b.z + a.w * b.w;
        }
        float dd = fmaxf(x2i + x2[j] - 2.f * dot, 0.f);
        if (dd < b2) {
            if (dd < b1) { b2 = b1; if (dd < b0) { b1 = b0; b0 = dd; } else b1 = dd; }
            else b2 = dd;
        }
    }
#pragma unroll
    for (int off = 32; off > 0; off >>= 1) {
        float c0 = __shfl_xor(b0, off, 64);
        float c1 = __shfl_xor(b1, off, 64);
        float c2 = __shfl_xor(b2, off, 64);
        float m0, m1, m2;
        if (b0 <= c0) {
            m0 = b0;
            if (b1 <= c0) { m1 = b1; m2 = fminf(b2, c0); }
            else { m1 = c0; m2 = fminf(b1, c1); }
        } else {
            m0 = c0;
            if (c1 <= b0) { m1 = c1; m2 = fminf(c2, b0); }
            else { m1 = b0; m2 = fminf(c1, b1); }
        }
        b0 = m0; b1 = m1; b2 = m2;
    }
    if (t == 0) {
        targetd[3 * i + 0] = b0;
        targetd[3 * i + 1] = b1;
        targetd[3 * i + 2] = b2;
        radii[i] = 1.f + b2;
        atomicAdd(&accd[0], (double)(b0 + b1 + b2));
    }
}

// ---------------- sort radii + suffix sums + bin table ----------------
__global__ __launch_bounds__(1024) void sort_scan_kernel(const float* __restrict__ radii,
                                                         float* __restrict__ sorted_r,
                                                         float* __restrict__ ssum,
                                                         unsigned short* __restrict__ lotab) {
    __shared__ float s[N];
    __shared__ float aux[1024];
    int t = threadIdx.x;
    for (int i = t; i < N; i += 1024) s[i] = radii[i];
    __syncthreads();
    for (int k = 2; k <= N; k <<= 1) {
        for (int j = k >> 1; j > 0; j >>= 1) {
            for (int i = t; i < N; i += 1024) {
                int ixj = i ^ j;
                if (ixj > i) {
                    bool up = ((i & k) == 0);
                    float a = s[i], b = s[ixj];
                    if ((a > b) == up) { s[i] = b; s[ixj] = a; }
                }
            }
            __syncthreads();
        }
    }
    float v0 = s[4 * t + 0], v1 = s[4 * t + 1], v2 = s[4 * t + 2], v3 = s[4 * t + 3];
    float tot = v0 + v1 + v2 + v3;
    aux[t] = tot;
    __syncthreads();
    for (int off = 1; off < 1024; off <<= 1) {
        float add = (t + off < 1024) ? aux[t + off] : 0.f;
        __syncthreads();
        aux[t] += add;
        __syncthreads();
    }
    float suf_next = aux[t] - tot;
    float s3 = v3 + suf_next;
    float s2 = v2 + s3;
    float s1 = v1 + s2;
    float s0 = v0 + s1;
    ssum[4 * t + 0] = s0;
    ssum[4 * t + 1] = s1;
    ssum[4 * t + 2] = s2;
    ssum[4 * t + 3] = s3;
    sorted_r[4 * t + 0] = v0;
    sorted_r[4 * t + 1] = v1;
    sorted_r[4 * t + 2] = v2;
    sorted_r[4 * t + 3] = v3;
    if (t == 0) ssum[N] = 0.f;
    __syncthreads();
    // bin table: lotab[b] = first index with s > d0 + b*binw
    float d0 = s[0], rmx = s[N - 1];
    float binw = fmaxf(rmx - d0, 1e-20f) / (float)NBINS;
    for (int b = t; b <= NBINS; b += 1024) {
        float v = d0 + binw * (float)b;
        int lo = 0, hi = N;
        while (lo < hi) {
            int mid = (lo + hi) >> 1;
            if (s[mid] <= v) lo = mid + 1; else hi = mid;
        }
        lotab[b] = (unsigned short)lo;
    }
}

// ---------------- fused bf16 MFMA Gram + push epilogue (upper-tri blocks) ----------------
#define SMEM_BYTES 34944
__global__ __launch_bounds__(256) void push_gemm_kernel(const float* __restrict__ X,
                                                        const float* __restrict__ x2,
                                                        const float* __restrict__ sorted_r,
                                                        const float* __restrict__ ssum,
                                                        const unsigned short* __restrict__ lotab,
                                                        double* __restrict__ accd) {
    __shared__ __align__(16) char smem[SMEM_BYTES];
    __shared__ float x2r[128], x2c[128];
    __shared__ float red[256];

    // triangular block decode: by <= bx
    int bid = blockIdx.x;
    int by = 0, rem = bid;
    while (rem >= 32 - by) { rem -= 32 - by; ++by; }
    int bx = by + rem;
    int rowBase = by * 128, colBase = bx * 128;

    int tid = threadIdx.x;
    int lane = tid & 63;
    int wv = tid >> 6;
    int wy = wv >> 1, wx = wv & 1;

    floatx4 acc4[4][4];
#pragma unroll
    for (int m = 0; m < 4; ++m)
#pragma unroll
        for (int n = 0; n < 4; ++n) acc4[m][n] = (floatx4){0.f, 0.f, 0.f, 0.f};

    if (tid < 128) { x2r[tid] = x2[rowBase + tid]; x2c[tid] = x2[colBase + tid]; }

    for (int k0 = 0; k0 < DF; k0 += 64) {
        if (k0) __syncthreads();
        // stage A (rows from rowBase) and B (rows from colBase), frag-major layout
#pragma unroll
        for (int cch = 0; cch < 4; ++cch) {
            int did = tid + (cch << 8);                 // 0..1023
            int row = ((did >> 7) << 4) | (did & 15);   // 0..127
            int kb = (did >> 4) & 7;                    // 0..7 (8 bf16 each)
            const float* srcA = X + (size_t)(rowBase + row) * DF + k0 + kb * 8;
            const float* srcB = X + (size_t)(colBase + row) * DF + k0 + kb * 8;
            float4 a0 = *(const float4*)srcA;
            float4 a1 = *(const float4*)(srcA + 4);
            float4 e0 = *(const float4*)srcB;
            float4 e1 = *(const float4*)(srcB + 4);
            ushort8v va, vb;
            va[0] = f2bf(a0.x); va[1] = f2bf(a0.y); va[2] = f2bf(a0.z); va[3] = f2bf(a0.w);
            va[4] = f2bf(a1.x); va[5] = f2bf(a1.y); va[6] = f2bf(a1.z); va[7] = f2bf(a1.w);
            vb[0] = f2bf(e0.x); vb[1] = f2bf(e0.y); vb[2] = f2bf(e0.z); vb[3] = f2bf(e0.w);
            vb[4] = f2bf(e1.x); vb[5] = f2bf(e1.y); vb[6] = f2bf(e1.z); vb[7] = f2bf(e1.w);
            *((ushort8v*)(smem + (did << 4))) = va;
            *((ushort8v*)(smem + 16384 + (did << 4))) = vb;
        }
        __syncthreads();
#pragma unroll
        for (int kk = 0; kk < 2; ++kk) {
            short8v a[4], b[4];
#pragma unroll
            for (int m = 0; m < 4; ++m)
                a[m] = *((const short8v*)(smem + (((wy * 4 + m) * 2 + kk) << 10) + (lane << 4)));
#pragma unroll
            for (int n = 0; n < 4; ++n)
                b[n] = *((const short8v*)(smem + 16384 + (((wx * 4 + n) * 2 + kk) << 10) + (lane << 4)));
#pragma unroll
            for (int m = 0; m < 4; ++m)
#pragma unroll
                for (int n = 0; n < 4; ++n)
                    acc4[m][n] = __builtin_amdgcn_mfma_f32_16x16x32_bf16(a[m], b[n], acc4[m][n], 0, 0, 0);
        }
    }
    __syncthreads();

    // overlay epilogue tables onto GEMM LDS
    float* rs = (float*)smem;                // 4096
    float* ss = rs + N;                      // 4097
    unsigned short* lot = (unsigned short*)(ss + N + 1);  // 1025
    for (int i = tid; i < N; i += 256) rs[i] = sorted_r[i];
    for (int i = tid; i < N + 1; i += 256) ss[i] = ssum[i];
    for (int i = tid; i <= NBINS; i += 256) lot[i] = lotab[i];
    __syncthreads();

    float d0v = rs[0];
    float rmaxv = rs[N - 1];
    float invw = (float)NBINS / fmaxf(rmaxv - d0v, 1e-20f);
    float ss0 = ss[0];
    bool diag = (by == bx);

    float local = 0.f;
    int g = lane >> 4;
    int cl = lane & 15;
#pragma unroll
    for (int m = 0; m < 4; ++m) {
#pragma unroll
        for (int n = 0; n < 4; ++n) {
            floatx4 v = acc4[m][n];
            int gcl = wx * 64 + n * 16 + cl;
            float x2cv = x2c[gcl];
#pragma unroll
            for (int r = 0; r < 4; ++r) {
                int grl = wy * 64 + m * 16 + g * 4 + r;
                if (diag && grl == gcl) continue;    // exact diagonal exclusion
                float d = fmaxf(x2r[grl] + x2cv - 2.f * v[r], 0.f);
                if (d >= rmaxv) continue;            // f(d) = 0
                if (d < d0v) {
                    local += ss0 - d * (float)N;     // all radii > d
                } else {
                    int b = (int)((d - d0v) * invw);
                    b = max(0, min(b, NBINS - 1));
                    int lo = lot[b == 0 ? 0 : b - 1];
                    int hi = lot[min(b + 2, NBINS)];
                    while (lo < hi) {
                        int mid = (lo + hi) >> 1;
                        if (rs[mid] <= d) lo = mid + 1; else hi = mid;
                    }
                    local += ss[lo] - d * (float)(N - lo);
                }
            }
        }
    }
    red[tid] = local;
    __syncthreads();
    for (int s2 = 128; s2 > 0; s2 >>= 1) {
        if (tid < s2) red[tid] += red[tid + s2];
        __syncthreads();
    }
    if (tid == 0) {
        float wt = diag ? 1.f : 2.f;
        atomicAdd(&accd[1], (double)(wt * red[0]));
    }
}

// ---------------- subtract f(d) at the 3N neighbor pairs ----------------
__global__ __launch_bounds__(256) void nbr_sub_kernel(const float* __restrict__ targetd,
                                                      const float* __restrict__ sorted_r,
                                                      const float* __restrict__ ssum,
                                                      double* __restrict__ accd) {
    __shared__ float red[256];
    int idx = blockIdx.x * 256 + threadIdx.x;
    float local = 0.f;
    if (idx < 3 * N) {
        float d = targetd[idx];
        int lo = 0, hi = N;
        while (lo < hi) {
            int mid = (lo + hi) >> 1;
            if (sorted_r[mid] <= d) lo = mid + 1; else hi = mid;
        }
        local = ssum[lo] - d * (float)(N - lo);
    }
    red[threadIdx.x] = local;
    __syncthreads();
    for (int s2 = 128; s2 > 0; s2 >>= 1) {
        if (threadIdx.x < s2) red[threadIdx.x] += red[threadIdx.x + s2];
        __syncthreads();
    }
    if (threadIdx.x == 0) atomicAdd(&accd[2], (double)red[0]);
}

// ---------------- finalize ----------------
__global__ void finalize_kernel(const double* __restrict__ accd, float* __restrict__ out) {
    out[0] = (float)((accd[0] + accd[1] - accd[2]) / (double)N);
}

extern "C" void kernel_launch(void* const* d_in, const int* in_sizes, int n_in,
                              void* d_out, int out_size, void* d_ws, size_t ws_size,
                              hipStream_t stream) {
    const float* X = (const float*)d_in[0];
    const int* labels = (const int*)d_in[1];
    float* out = (float*)d_out;

    double* accd  = (double*)d_ws;               // 8 doubles
    float* x2     = (float*)(accd + 8);          // 4096
    float* radii  = x2 + N;                      // 4096
    float* sorted = radii + N;                   // 4096
    float* ssum   = sorted + N;                  // 4104 (4097 used)
    float* targetd = ssum + 4104;                // 12288
    int* cnt      = (int*)(targetd + 3 * N);     // 64
    int* members  = cnt + 64;                    // 16384
    unsigned short* lotab = (unsigned short*)(members + 64 * MAXM); // 1032

    hipLaunchKernelGGL(zero_acc_kernel, dim3(1), dim3(64), 0, stream, accd);
    hipLaunchKernelGGL(x2_kernel, dim3(N / 4), dim3(256), 0, stream, X, x2);
    hipLaunchKernelGGL(bucket_kernel, dim3(1), dim3(1024), 0, stream, labels, cnt, members);
    hipLaunchKernelGGL(knn_kernel, dim3(N), dim3(64), 0, stream,
                       X, labels, x2, cnt, members, radii, targetd, accd);
    hipLaunchKernelGGL(sort_scan_kernel, dim3(1), dim3(1024), 0, stream,
                       radii, sorted, ssum, lotab);
    hipLaunchKernelGGL(push_gemm_kernel, dim3(528), dim3(256), 0, stream,
                       X, x2, sorted, ssum, lotab, accd);
    hipLaunchKernelGGL(nbr_sub_kernel, dim3((3 * N + 255) / 256), dim3(256), 0, stream,
                       targetd, sorted, ssum, accd);
    hipLaunchKernelGGL(finalize_kernel, dim3(1), dim3(1), 0, stream, accd, out);
}

// Round 3
// 222.684 us; speedup vs baseline: 2.7300x; 1.3141x over previous
//
#include <hip/hip_runtime.h>
#include <hip/hip_bf16.h>
#include <float.h>

#define N 4096
#define DF 256
#define NBINS 1024
#define MAXM 256

typedef __attribute__((ext_vector_type(8))) short short8v;
typedef __attribute__((ext_vector_type(8))) unsigned short ushort8v;
typedef __attribute__((ext_vector_type(4))) float floatx4;

__device__ inline unsigned short f2bf(float f) {
    __hip_bfloat16 h = __float2bfloat16(f);
    return *reinterpret_cast<unsigned short*>(&h);
}

// ---------------- row squared norms: 4 rows/block, wave per row ----------------
__global__ __launch_bounds__(256) void x2_kernel(const float* __restrict__ X,
                                                 float* __restrict__ x2) {
    int row = blockIdx.x * 4 + (threadIdx.x >> 6);
    int l = threadIdx.x & 63;
    float4 v = ((const float4*)(X + (size_t)row * DF))[l];
    float s = v.x * v.x + v.y * v.y + v.z * v.z + v.w * v.w;
#pragma unroll
    for (int off = 32; off > 0; off >>= 1) s += __shfl_xor(s, off, 64);
    if (l == 0) x2[row] = s;
}

// ---------------- class bucketing (+ accumulator zeroing) ----------------
__global__ __launch_bounds__(1024) void bucket_kernel(const int* __restrict__ labels,
                                                      int* __restrict__ cnt,
                                                      int* __restrict__ members,
                                                      double* __restrict__ accd) {
    __shared__ int scnt[64];
    int t = threadIdx.x;
    if (t < 8) accd[t] = 0.0;
    if (t < 64) scnt[t] = 0;
    __syncthreads();
    for (int i = t; i < N; i += 1024) {
        int c = labels[i];
        int pos = atomicAdd(&scnt[c], 1);
        if (pos < MAXM) members[(c << 8) + pos] = i;
    }
    __syncthreads();
    if (t < 64) cnt[t] = min(scnt[t], MAXM);
}

// ---------------- per-row 3-NN among same-class (1 wave / row, coalesced) ----------------
__global__ __launch_bounds__(64) void knn_kernel(const float* __restrict__ X,
                                                 const int* __restrict__ labels,
                                                 const float* __restrict__ x2,
                                                 const int* __restrict__ cnt,
                                                 const int* __restrict__ members,
                                                 float* __restrict__ radii,
                                                 float* __restrict__ targetd,
                                                 double* __restrict__ accd) {
    int i = blockIdx.x;
    int l = threadIdx.x;           // 0..63
    __shared__ float4 xi[64];
    xi[l] = ((const float4*)(X + (size_t)i * DF))[l];
    __syncthreads();
    int c = labels[i];
    int m = cnt[c];
    const int* mem = members + (c << 8);
    float x2i = x2[i];
    int g = l >> 4, sl = l & 15;
    float b0 = FLT_MAX, b1 = FLT_MAX, b2 = FLT_MAX;
#pragma unroll 2
    for (int base = 0; base < m; base += 4) {
        int jj = base + g;
        int j = (jj < m) ? mem[jj] : -1;
        float dot = 0.f;
        if (j >= 0) {
            const float4* xr = (const float4*)(X + (size_t)j * DF);
#pragma unroll
            for (int p = 0; p < 4; ++p) {
                float4 a = xr[p * 16 + sl];
                float4 b = xi[p * 16 + sl];
                dot += a.x * b.x + a.y * b.y + a.z * b.z + a.w * b.w;
            }
        }
        // reduce dot within 16-lane group (butterfly: all lanes get the sum)
#pragma unroll
        for (int off = 1; off < 16; off <<= 1) dot += __shfl_xor(dot, off, 64);
        float dd;
        if (j < 0 || j == i) dd = FLT_MAX;
        else dd = fmaxf(x2i + x2[j] - 2.f * dot, 0.f);
        if (dd < b2) {
            if (dd < b1) { b2 = b1; if (dd < b0) { b1 = b0; b0 = dd; } else b1 = dd; }
            else b2 = dd;
        }
    }
    // merge sorted triples across the 4 groups
#pragma unroll
    for (int off = 16; off <= 32; off <<= 1) {
        float c0 = __shfl_xor(b0, off, 64);
        float c1 = __shfl_xor(b1, off, 64);
        float c2 = __shfl_xor(b2, off, 64);
        float m0, m1, m2;
        if (b0 <= c0) {
            m0 = b0;
            if (b1 <= c0) { m1 = b1; m2 = fminf(b2, c0); }
            else { m1 = c0; m2 = fminf(b1, c1); }
        } else {
            m0 = c0;
            if (c1 <= b0) { m1 = c1; m2 = fminf(c2, b0); }
            else { m1 = b0; m2 = fminf(c1, b1); }
        }
        b0 = m0; b1 = m1; b2 = m2;
    }
    if (l == 0) {
        targetd[3 * i + 0] = b0;
        targetd[3 * i + 1] = b1;
        targetd[3 * i + 2] = b2;
        radii[i] = 1.f + b2;
        atomicAdd(&accd[0], (double)(b0 + b1 + b2));
    }
}

// ---------------- counting sort + suffix sums + bin table + neighbor subtract ----------------
__device__ inline int bsearch_gt(const float* arr, float d) {
    int lo = 0, hi = N;
    while (lo < hi) {
        int mid = (lo + hi) >> 1;
        if (arr[mid] <= d) lo = mid + 1; else hi = mid;
    }
    return lo;
}

__global__ __launch_bounds__(1024) void sort_scan_kernel(const float* __restrict__ radii,
                                                         const float* __restrict__ targetd,
                                                         float* __restrict__ sorted_r,
                                                         float* __restrict__ ssum,
                                                         unsigned short* __restrict__ lotab,
                                                         double* __restrict__ accd) {
    __shared__ float t2[N];
    __shared__ int bcnt[N];
    __shared__ float aux[64];
    __shared__ int iaux[16];
    int t = threadIdx.x;
    int wid = t >> 6, lane = t & 63;

    float4 vv = ((const float4*)radii)[t];
    float v0 = vv.x, v1 = vv.y, v2 = vv.z, v3 = vv.w;

    // min/max reduce
    float mn = fminf(fminf(v0, v1), fminf(v2, v3));
    float mx = fmaxf(fmaxf(v0, v1), fmaxf(v2, v3));
#pragma unroll
    for (int off = 32; off > 0; off >>= 1) {
        mn = fminf(mn, __shfl_xor(mn, off, 64));
        mx = fmaxf(mx, __shfl_xor(mx, off, 64));
    }
    if (lane == 0) { aux[wid] = mn; aux[wid + 16] = mx; }
    bcnt[t] = 0; bcnt[t + 1024] = 0; bcnt[t + 2048] = 0; bcnt[t + 3072] = 0;
    __syncthreads();
    mn = aux[0]; mx = aux[16];
    for (int w = 1; w < 16; ++w) { mn = fminf(mn, aux[w]); mx = fmaxf(mx, aux[w + 16]); }
    float range = fmaxf(mx - mn, 1e-30f);
    float scale = (float)N / range * (1.f - 1e-6f);

    int b0i = max(0, min((int)((v0 - mn) * scale), N - 1));
    int b1i = max(0, min((int)((v1 - mn) * scale), N - 1));
    int b2i = max(0, min((int)((v2 - mn) * scale), N - 1));
    int b3i = max(0, min((int)((v3 - mn) * scale), N - 1));
    atomicAdd(&bcnt[b0i], 1); atomicAdd(&bcnt[b1i], 1);
    atomicAdd(&bcnt[b2i], 1); atomicAdd(&bcnt[b3i], 1);
    __syncthreads();

    // exclusive prefix of bin counts -> starts (wave shuffle scan)
    int c0i = bcnt[4 * t], c1i = bcnt[4 * t + 1], c2i = bcnt[4 * t + 2], c3i = bcnt[4 * t + 3];
    int tot_i = c0i + c1i + c2i + c3i;
    int sc = tot_i;
#pragma unroll
    for (int off = 1; off < 64; off <<= 1) {
        int y = __shfl_up(sc, off, 64);
        if (lane >= off) sc += y;
    }
    if (lane == 63) iaux[wid] = sc;
    __syncthreads();
    if (t < 16) {
        int wv = iaux[t];
        int s = wv;
#pragma unroll
        for (int off = 1; off < 16; off <<= 1) {
            int y = __shfl_up(s, off, 64);
            if (t >= off) s += y;
        }
        iaux[t] = s - wv;
    }
    __syncthreads();
    int base = iaux[wid] + (sc - tot_i);
    int e0 = base, e1 = base + c0i, e2 = e1 + c1i, e3 = e2 + c2i;
    bcnt[4 * t] = e0; bcnt[4 * t + 1] = e1; bcnt[4 * t + 2] = e2; bcnt[4 * t + 3] = e3;
    __syncthreads();

    // scatter
    t2[atomicAdd(&bcnt[b0i], 1)] = v0;
    t2[atomicAdd(&bcnt[b1i], 1)] = v1;
    t2[atomicAdd(&bcnt[b2i], 1)] = v2;
    t2[atomicAdd(&bcnt[b3i], 1)] = v3;
    __syncthreads();

    // per-bin insertion sort (bcnt[b] is now end_b; start_b = end_{b-1})
#pragma unroll
    for (int r = 0; r < 4; ++r) {
        int b = 4 * t + r;
        int st = b ? bcnt[b - 1] : 0;
        int en = bcnt[b];
        for (int a = st + 1; a < en; ++a) {
            float key = t2[a];
            int q = a - 1;
            while (q >= st && t2[q] > key) { t2[q + 1] = t2[q]; --q; }
            t2[q + 1] = key;
        }
    }
    __syncthreads();

    // suffix sums via shuffle scan
    float w0 = t2[4 * t], w1 = t2[4 * t + 1], w2 = t2[4 * t + 2], w3 = t2[4 * t + 3];
    float tot4 = w0 + w1 + w2 + w3;
    float sfx = tot4;
#pragma unroll
    for (int off = 1; off < 64; off <<= 1) {
        float y = __shfl_down(sfx, off, 64);
        if (lane + off < 64) sfx += y;
    }
    if (lane == 0) aux[wid] = sfx;
    __syncthreads();
    if (t < 16) {
        float x = aux[t];
        float s = x;
#pragma unroll
        for (int off = 1; off < 16; off <<= 1) {
            float y = __shfl_down(s, off, 64);
            if (t + off < 16) s += y;
        }
        aux[t] = s - x;
    }
    __syncthreads();
    float after = aux[wid] + (sfx - tot4);
    float q3 = w3 + after, q2 = w2 + q3, q1 = w1 + q2, q0 = w0 + q1;
    float* ssf = (float*)bcnt;   // overlay suffix sums for local lookups
    ssf[4 * t] = q0; ssf[4 * t + 1] = q1; ssf[4 * t + 2] = q2; ssf[4 * t + 3] = q3;
    ssum[4 * t] = q0; ssum[4 * t + 1] = q1; ssum[4 * t + 2] = q2; ssum[4 * t + 3] = q3;
    sorted_r[4 * t] = w0; sorted_r[4 * t + 1] = w1; sorted_r[4 * t + 2] = w2; sorted_r[4 * t + 3] = w3;
    if (t == 0) ssum[N] = 0.f;
    __syncthreads();

    // bin table for push epilogue
    float d0 = t2[0], rmx2 = t2[N - 1];
    float binw = fmaxf(rmx2 - d0, 1e-20f) / (float)NBINS;
    for (int e = t; e <= NBINS; e += 1024)
        lotab[e] = (unsigned short)bsearch_gt(t2, d0 + binw * (float)e);

    // neighbor-pair subtraction: f(d) at the 3N target-neighbor distances
    float loc = 0.f;
    for (int idx = t; idx < 3 * N; idx += 1024) {
        float d = targetd[idx];
        int lo = bsearch_gt(t2, d);
        if (lo < N) loc += ssf[lo] - d * (float)(N - lo);
    }
#pragma unroll
    for (int off = 32; off > 0; off >>= 1) loc += __shfl_xor(loc, off, 64);
    __syncthreads();
    if (lane == 0) aux[wid] = loc;
    __syncthreads();
    if (t == 0) {
        float s = 0.f;
        for (int w = 0; w < 16; ++w) s += aux[w];
        atomicAdd(&accd[2], (double)s);
    }
}

// ---------------- fused bf16 MFMA Gram + push epilogue (upper-tri blocks) ----------------
#define SMEM_BYTES 34944
__global__ __launch_bounds__(256) void push_gemm_kernel(const float* __restrict__ X,
                                                        const float* __restrict__ x2,
                                                        const float* __restrict__ sorted_r,
                                                        const float* __restrict__ ssum,
                                                        const unsigned short* __restrict__ lotab,
                                                        double* __restrict__ accd) {
    __shared__ __align__(16) char smem[SMEM_BYTES];
    __shared__ float x2r[128], x2c[128];
    __shared__ float red[256];

    int bid = blockIdx.x;
    int by = 0, rem = bid;
    while (rem >= 32 - by) { rem -= 32 - by; ++by; }
    int bx = by + rem;
    int rowBase = by * 128, colBase = bx * 128;

    int tid = threadIdx.x;
    int lane = tid & 63;
    int wv = tid >> 6;
    int wy = wv >> 1, wx = wv & 1;

    floatx4 acc4[4][4];
#pragma unroll
    for (int m = 0; m < 4; ++m)
#pragma unroll
        for (int n = 0; n < 4; ++n) acc4[m][n] = (floatx4){0.f, 0.f, 0.f, 0.f};

    if (tid < 128) { x2r[tid] = x2[rowBase + tid]; x2c[tid] = x2[colBase + tid]; }

    for (int k0 = 0; k0 < DF; k0 += 64) {
        if (k0) __syncthreads();
#pragma unroll
        for (int cch = 0; cch < 4; ++cch) {
            int did = tid + (cch << 8);
            int row = ((did >> 7) << 4) | (did & 15);
            int kb = (did >> 4) & 7;
            const float* srcA = X + (size_t)(rowBase + row) * DF + k0 + kb * 8;
            const float* srcB = X + (size_t)(colBase + row) * DF + k0 + kb * 8;
            float4 a0 = *(const float4*)srcA;
            float4 a1 = *(const float4*)(srcA + 4);
            float4 e0 = *(const float4*)srcB;
            float4 e1 = *(const float4*)(srcB + 4);
            ushort8v va, vb;
            va[0] = f2bf(a0.x); va[1] = f2bf(a0.y); va[2] = f2bf(a0.z); va[3] = f2bf(a0.w);
            va[4] = f2bf(a1.x); va[5] = f2bf(a1.y); va[6] = f2bf(a1.z); va[7] = f2bf(a1.w);
            vb[0] = f2bf(e0.x); vb[1] = f2bf(e0.y); vb[2] = f2bf(e0.z); vb[3] = f2bf(e0.w);
            vb[4] = f2bf(e1.x); vb[5] = f2bf(e1.y); vb[6] = f2bf(e1.z); vb[7] = f2bf(e1.w);
            *((ushort8v*)(smem + (did << 4))) = va;
            *((ushort8v*)(smem + 16384 + (did << 4))) = vb;
        }
        __syncthreads();
#pragma unroll
        for (int kk = 0; kk < 2; ++kk) {
            short8v a[4], b[4];
#pragma unroll
            for (int m = 0; m < 4; ++m)
                a[m] = *((const short8v*)(smem + (((wy * 4 + m) * 2 + kk) << 10) + (lane << 4)));
#pragma unroll
            for (int n = 0; n < 4; ++n)
                b[n] = *((const short8v*)(smem + 16384 + (((wx * 4 + n) * 2 + kk) << 10) + (lane << 4)));
#pragma unroll
            for (int m = 0; m < 4; ++m)
#pragma unroll
                for (int n = 0; n < 4; ++n)
                    acc4[m][n] = __builtin_amdgcn_mfma_f32_16x16x32_bf16(a[m], b[n], acc4[m][n], 0, 0, 0);
        }
    }
    __syncthreads();

    float* rs = (float*)smem;
    float* ss = rs + N;
    unsigned short* lot = (unsigned short*)(ss + N + 1);
    for (int i = tid; i < N; i += 256) rs[i] = sorted_r[i];
    for (int i = tid; i < N + 1; i += 256) ss[i] = ssum[i];
    for (int i = tid; i <= NBINS; i += 256) lot[i] = lotab[i];
    __syncthreads();

    float d0v = rs[0];
    float rmaxv = rs[N - 1];
    float invw = (float)NBINS / fmaxf(rmaxv - d0v, 1e-20f);
    float ss0 = ss[0];
    bool diag = (by == bx);

    float local = 0.f;
    int g = lane >> 4;
    int cl = lane & 15;
#pragma unroll
    for (int m = 0; m < 4; ++m) {
#pragma unroll
        for (int n = 0; n < 4; ++n) {
            floatx4 v = acc4[m][n];
            int gcl = wx * 64 + n * 16 + cl;
            float x2cv = x2c[gcl];
#pragma unroll
            for (int r = 0; r < 4; ++r) {
                int grl = wy * 64 + m * 16 + g * 4 + r;
                if (diag && grl == gcl) continue;
                float d = fmaxf(x2r[grl] + x2cv - 2.f * v[r], 0.f);
                if (d >= rmaxv) continue;
                if (d < d0v) {
                    local += ss0 - d * (float)N;
                } else {
                    int b = (int)((d - d0v) * invw);
                    b = max(0, min(b, NBINS - 1));
                    int lo = lot[b == 0 ? 0 : b - 1];
                    int hi = lot[min(b + 2, NBINS)];
                    while (lo < hi) {
                        int mid = (lo + hi) >> 1;
                        if (rs[mid] <= d) lo = mid + 1; else hi = mid;
                    }
                    local += ss[lo] - d * (float)(N - lo);
                }
            }
        }
    }
    red[tid] = local;
    __syncthreads();
    for (int s2 = 128; s2 > 0; s2 >>= 1) {
        if (tid < s2) red[tid] += red[tid + s2];
        __syncthreads();
    }
    if (tid == 0) {
        float wt = diag ? 1.f : 2.f;
        atomicAdd(&accd[1], (double)(wt * red[0]));
    }
}

// ---------------- finalize ----------------
__global__ void finalize_kernel(const double* __restrict__ accd, float* __restrict__ out) {
    out[0] = (float)((accd[0] + accd[1] - accd[2]) / (double)N);
}

extern "C" void kernel_launch(void* const* d_in, const int* in_sizes, int n_in,
                              void* d_out, int out_size, void* d_ws, size_t ws_size,
                              hipStream_t stream) {
    const float* X = (const float*)d_in[0];
    const int* labels = (const int*)d_in[1];
    float* out = (float*)d_out;

    double* accd  = (double*)d_ws;               // 8 doubles
    float* x2     = (float*)(accd + 8);          // 4096
    float* radii  = x2 + N;                      // 4096 (16B aligned)
    float* sorted = radii + N;                   // 4096
    float* ssum   = sorted + N;                  // 4104 (4097 used)
    float* targetd = ssum + 4104;                // 12288
    int* cnt      = (int*)(targetd + 3 * N);     // 64
    int* members  = cnt + 64;                    // 16384
    unsigned short* lotab = (unsigned short*)(members + 64 * MAXM); // 1032

    hipLaunchKernelGGL(x2_kernel, dim3(N / 4), dim3(256), 0, stream, X, x2);
    hipLaunchKernelGGL(bucket_kernel, dim3(1), dim3(1024), 0, stream, labels, cnt, members, accd);
    hipLaunchKernelGGL(knn_kernel, dim3(N), dim3(64), 0, stream,
                       X, labels, x2, cnt, members, radii, targetd, accd);
    hipLaunchKernelGGL(sort_scan_kernel, dim3(1), dim3(1024), 0, stream,
                       radii, targetd, sorted, ssum, lotab, accd);
    hipLaunchKernelGGL(push_gemm_kernel, dim3(528), dim3(256), 0, stream,
                       X, x2, sorted, ssum, lotab, accd);
    hipLaunchKernelGGL(finalize_kernel, dim3(1), dim3(1), 0, stream, accd, out);
}

// Round 4
// 154.254 us; speedup vs baseline: 3.9410x; 1.4436x over previous
//
#include <hip/hip_runtime.h>
#include <hip/hip_bf16.h>
#include <float.h>

#define N 4096
#define DF 256
#define NBINS2 4096
#define MAXM 256

typedef __attribute__((ext_vector_type(8))) short short8v;
typedef __attribute__((ext_vector_type(8))) unsigned short ushort8v;
typedef __attribute__((ext_vector_type(4))) float floatx4;

__device__ inline unsigned short f2bf(float f) {
    __hip_bfloat16 h = __float2bfloat16(f);
    return *reinterpret_cast<unsigned short*>(&h);
}

__device__ inline void gload_lds16(const void* g, void* l) {
    __builtin_amdgcn_global_load_lds((const __attribute__((address_space(1))) void*)g,
                                     (__attribute__((address_space(3))) void*)l, 16, 0, 0);
}

// ---------------- row squared norms ----------------
__global__ __launch_bounds__(256) void x2_kernel(const float* __restrict__ X,
                                                 float* __restrict__ x2) {
    int row = blockIdx.x * 4 + (threadIdx.x >> 6);
    int l = threadIdx.x & 63;
    float4 v = ((const float4*)(X + (size_t)row * DF))[l];
    float s = v.x * v.x + v.y * v.y + v.z * v.z + v.w * v.w;
#pragma unroll
    for (int off = 32; off > 0; off >>= 1) s += __shfl_xor(s, off, 64);
    if (l == 0) x2[row] = s;
}

// ---------------- fp32 -> bf16 copy of X ----------------
__global__ __launch_bounds__(256) void cvt_kernel(const float* __restrict__ X,
                                                  __hip_bfloat16* __restrict__ Xb) {
    int i = blockIdx.x * 256 + threadIdx.x;
    float4 v = ((const float4*)X)[i];
    ushort4 o;
    o.x = f2bf(v.x); o.y = f2bf(v.y); o.z = f2bf(v.z); o.w = f2bf(v.w);
    ((ushort4*)Xb)[i] = o;
}

// ---------------- class bucketing (+ accumulator zeroing) ----------------
__global__ __launch_bounds__(1024) void bucket_kernel(const int* __restrict__ labels,
                                                      int* __restrict__ cnt,
                                                      int* __restrict__ members,
                                                      double* __restrict__ accd) {
    __shared__ int scnt[64];
    int t = threadIdx.x;
    if (t < 8) accd[t] = 0.0;
    if (t < 64) scnt[t] = 0;
    __syncthreads();
    for (int i = t; i < N; i += 1024) {
        int c = labels[i];
        int pos = atomicAdd(&scnt[c], 1);
        if (pos < MAXM) members[(c << 8) + pos] = i;
    }
    __syncthreads();
    if (t < 64) cnt[t] = min(scnt[t], MAXM);
}

// ---------------- per-row 3-NN among same-class (1 wave / row, coalesced) ----------------
__global__ __launch_bounds__(64) void knn_kernel(const float* __restrict__ X,
                                                 const int* __restrict__ labels,
                                                 const float* __restrict__ x2,
                                                 const int* __restrict__ cnt,
                                                 const int* __restrict__ members,
                                                 float* __restrict__ radii,
                                                 float* __restrict__ targetd,
                                                 double* __restrict__ accd) {
    int i = blockIdx.x;
    int l = threadIdx.x;
    __shared__ float4 xi[64];
    xi[l] = ((const float4*)(X + (size_t)i * DF))[l];
    __syncthreads();
    int c = labels[i];
    int m = cnt[c];
    const int* mem = members + (c << 8);
    float x2i = x2[i];
    int g = l >> 4, sl = l & 15;
    float b0 = FLT_MAX, b1 = FLT_MAX, b2 = FLT_MAX;
#pragma unroll 2
    for (int base = 0; base < m; base += 4) {
        int jj = base + g;
        int j = (jj < m) ? mem[jj] : -1;
        float dot = 0.f;
        if (j >= 0) {
            const float4* xr = (const float4*)(X + (size_t)j * DF);
#pragma unroll
            for (int p = 0; p < 4; ++p) {
                float4 a = xr[p * 16 + sl];
                float4 b = xi[p * 16 + sl];
                dot += a.x * b.x + a.y * b.y + a.z * b.z + a.w * b.w;
            }
        }
#pragma unroll
        for (int off = 1; off < 16; off <<= 1) dot += __shfl_xor(dot, off, 64);
        float dd;
        if (j < 0 || j == i) dd = FLT_MAX;
        else dd = fmaxf(x2i + x2[j] - 2.f * dot, 0.f);
        if (dd < b2) {
            if (dd < b1) { b2 = b1; if (dd < b0) { b1 = b0; b0 = dd; } else b1 = dd; }
            else b2 = dd;
        }
    }
#pragma unroll
    for (int off = 16; off <= 32; off <<= 1) {
        float c0 = __shfl_xor(b0, off, 64);
        float c1 = __shfl_xor(b1, off, 64);
        float c2 = __shfl_xor(b2, off, 64);
        float m0, m1, m2;
        if (b0 <= c0) {
            m0 = b0;
            if (b1 <= c0) { m1 = b1; m2 = fminf(b2, c0); }
            else { m1 = c0; m2 = fminf(b1, c1); }
        } else {
            m0 = c0;
            if (c1 <= b0) { m1 = c1; m2 = fminf(c2, b0); }
            else { m1 = b0; m2 = fminf(c1, b1); }
        }
        b0 = m0; b1 = m1; b2 = m2;
    }
    if (l == 0) {
        targetd[3 * i + 0] = b0;
        targetd[3 * i + 1] = b1;
        targetd[3 * i + 2] = b2;
        radii[i] = 1.f + b2;
        atomicAdd(&accd[0], (double)(b0 + b1 + b2));
    }
}

// ---------------- counting sort + chord table + neighbor subtract ----------------
__device__ inline int bsearch_gt(const float* arr, float d) {
    int lo = 0, hi = N;
    while (lo < hi) {
        int mid = (lo + hi) >> 1;
        if (arr[mid] <= d) lo = mid + 1; else hi = mid;
    }
    return lo;
}

__global__ __launch_bounds__(1024) void sort_scan_kernel(const float* __restrict__ radii,
                                                         const float* __restrict__ targetd,
                                                         float2* __restrict__ ftab_g,
                                                         float* __restrict__ hdr,
                                                         double* __restrict__ accd) {
    __shared__ float t2[N];
    __shared__ int bcnt[N];
    __shared__ float fv[NBINS2 + 1];
    __shared__ float aux[64];
    __shared__ int iaux[16];
    int t = threadIdx.x;
    int wid = t >> 6, lane = t & 63;

    float4 vv = ((const float4*)radii)[t];
    float v0 = vv.x, v1 = vv.y, v2 = vv.z, v3 = vv.w;

    float mn = fminf(fminf(v0, v1), fminf(v2, v3));
    float mx = fmaxf(fmaxf(v0, v1), fmaxf(v2, v3));
#pragma unroll
    for (int off = 32; off > 0; off >>= 1) {
        mn = fminf(mn, __shfl_xor(mn, off, 64));
        mx = fmaxf(mx, __shfl_xor(mx, off, 64));
    }
    if (lane == 0) { aux[wid] = mn; aux[wid + 16] = mx; }
    bcnt[t] = 0; bcnt[t + 1024] = 0; bcnt[t + 2048] = 0; bcnt[t + 3072] = 0;
    __syncthreads();
    mn = aux[0]; mx = aux[16];
    for (int w = 1; w < 16; ++w) { mn = fminf(mn, aux[w]); mx = fmaxf(mx, aux[w + 16]); }
    float range = fmaxf(mx - mn, 1e-30f);
    float scale = (float)N / range * (1.f - 1e-6f);

    int b0i = max(0, min((int)((v0 - mn) * scale), N - 1));
    int b1i = max(0, min((int)((v1 - mn) * scale), N - 1));
    int b2i = max(0, min((int)((v2 - mn) * scale), N - 1));
    int b3i = max(0, min((int)((v3 - mn) * scale), N - 1));
    atomicAdd(&bcnt[b0i], 1); atomicAdd(&bcnt[b1i], 1);
    atomicAdd(&bcnt[b2i], 1); atomicAdd(&bcnt[b3i], 1);
    __syncthreads();

    int c0i = bcnt[4 * t], c1i = bcnt[4 * t + 1], c2i = bcnt[4 * t + 2], c3i = bcnt[4 * t + 3];
    int tot_i = c0i + c1i + c2i + c3i;
    int sc = tot_i;
#pragma unroll
    for (int off = 1; off < 64; off <<= 1) {
        int y = __shfl_up(sc, off, 64);
        if (lane >= off) sc += y;
    }
    if (lane == 63) iaux[wid] = sc;
    __syncthreads();
    if (t < 16) {
        int wv2 = iaux[t];
        int s = wv2;
#pragma unroll
        for (int off = 1; off < 16; off <<= 1) {
            int y = __shfl_up(s, off, 64);
            if (t >= off) s += y;
        }
        iaux[t] = s - wv2;
    }
    __syncthreads();
    int base = iaux[wid] + (sc - tot_i);
    int e0 = base, e1 = base + c0i, e2 = e1 + c1i, e3 = e2 + c2i;
    bcnt[4 * t] = e0; bcnt[4 * t + 1] = e1; bcnt[4 * t + 2] = e2; bcnt[4 * t + 3] = e3;
    __syncthreads();

    t2[atomicAdd(&bcnt[b0i], 1)] = v0;
    t2[atomicAdd(&bcnt[b1i], 1)] = v1;
    t2[atomicAdd(&bcnt[b2i], 1)] = v2;
    t2[atomicAdd(&bcnt[b3i], 1)] = v3;
    __syncthreads();

#pragma unroll
    for (int r = 0; r < 4; ++r) {
        int b = 4 * t + r;
        int st = b ? bcnt[b - 1] : 0;
        int en = bcnt[b];
        for (int a = st + 1; a < en; ++a) {
            float key = t2[a];
            int q = a - 1;
            while (q >= st && t2[q] > key) { t2[q + 1] = t2[q]; --q; }
            t2[q + 1] = key;
        }
    }
    __syncthreads();

    float w0 = t2[4 * t], w1 = t2[4 * t + 1], w2 = t2[4 * t + 2], w3 = t2[4 * t + 3];
    float tot4 = w0 + w1 + w2 + w3;
    float sfx = tot4;
#pragma unroll
    for (int off = 1; off < 64; off <<= 1) {
        float y = __shfl_down(sfx, off, 64);
        if (lane + off < 64) sfx += y;
    }
    if (lane == 0) aux[wid] = sfx;
    __syncthreads();
    if (t < 16) {
        float x = aux[t];
        float s = x;
#pragma unroll
        for (int off = 1; off < 16; off <<= 1) {
            float y = __shfl_down(s, off, 64);
            if (t + off < 16) s += y;
        }
        aux[t] = s - x;
    }
    __syncthreads();
    float after = aux[wid] + (sfx - tot4);
    float q3 = w3 + after, q2 = w2 + q3, q1 = w1 + q2, q0 = w0 + q1;
    float* ssf = (float*)bcnt;
    ssf[4 * t] = q0; ssf[4 * t + 1] = q1; ssf[4 * t + 2] = q2; ssf[4 * t + 3] = q3;
    __syncthreads();

    // exact f at uniform edges, then per-bin chords
    float d0 = t2[0], rmx2 = t2[N - 1];
    float wbin = fmaxf(rmx2 - d0, 1e-20f) / (float)NBINS2;
    for (int e = t; e <= NBINS2; e += 1024) {
        float x = d0 + wbin * (float)e;
        int lo = bsearch_gt(t2, x);
        float Sv = (lo < N) ? ssf[lo] : 0.f;
        fv[e] = Sv - x * (float)(N - lo);
    }
    __syncthreads();
    for (int b = t; b < NBINS2; b += 1024)
        ftab_g[b] = make_float2(fv[b], fv[b + 1] - fv[b]);
    if (t == 0) {
        hdr[0] = d0;
        hdr[1] = rmx2;
        hdr[2] = (float)NBINS2 / fmaxf(rmx2 - d0, 1e-20f);
        hdr[3] = ssf[0];   // sum of all radii
    }

    // exact neighbor-pair subtraction
    float loc = 0.f;
    for (int idx = t; idx < 3 * N; idx += 1024) {
        float d = targetd[idx];
        int lo = bsearch_gt(t2, d);
        if (lo < N) loc += ssf[lo] - d * (float)(N - lo);
    }
#pragma unroll
    for (int off = 32; off > 0; off >>= 1) loc += __shfl_xor(loc, off, 64);
    __syncthreads();
    if (lane == 0) aux[wid] = loc;
    __syncthreads();
    if (t == 0) {
        float s = 0.f;
        for (int w = 0; w < 16; ++w) s += aux[w];
        atomicAdd(&accd[2], (double)s);
    }
}

// ---------------- fused bf16 MFMA Gram + chord-table push epilogue ----------------
template<int USEXB>
__global__ __launch_bounds__(256) void push_gemm_kernel(const float* __restrict__ X,
                                                        const __hip_bfloat16* __restrict__ Xb,
                                                        const float* __restrict__ x2,
                                                        const float2* __restrict__ ftab_g,
                                                        const float* __restrict__ hdr,
                                                        double* __restrict__ accd) {
    __shared__ __align__(16) char smem[32768];
    __shared__ float x2r[128], x2c[128];
    __shared__ float red[256];

    int bid = blockIdx.x;
    int by = 0, rem = bid;
    while (rem >= 32 - by) { rem -= 32 - by; ++by; }
    int bx = by + rem;
    int rowBase = by * 128, colBase = bx * 128;

    int tid = threadIdx.x;
    int lane = tid & 63;
    int wv = tid >> 6;
    int wy = wv >> 1, wx = wv & 1;

    floatx4 acc4[4][4];
#pragma unroll
    for (int m = 0; m < 4; ++m)
#pragma unroll
        for (int n = 0; n < 4; ++n) acc4[m][n] = (floatx4){0.f, 0.f, 0.f, 0.f};

    if (tid < 128) { x2r[tid] = x2[rowBase + tid]; x2c[tid] = x2[colBase + tid]; }

    for (int k0 = 0; k0 < DF; k0 += 64) {
        if (k0) __syncthreads();
        if (USEXB) {
            const __hip_bfloat16* Ab = Xb + (size_t)rowBase * DF;
            const __hip_bfloat16* Bb = Xb + (size_t)colBase * DF;
#pragma unroll
            for (int i = 0; i < 4; ++i) {
                int did = wv * 256 + i * 64 + lane;
                int row = ((did >> 7) << 4) | (did & 15);
                int kb = (did >> 4) & 7;
                size_t goff = (size_t)row * DF + k0 + kb * 8;
                char* ldsA = smem + (size_t)(wv * 256 + i * 64) * 16;
                gload_lds16(Ab + goff, ldsA);
                gload_lds16(Bb + goff, ldsA + 16384);
            }
        } else {
#pragma unroll
            for (int cch = 0; cch < 4; ++cch) {
                int did = tid + (cch << 8);
                int row = ((did >> 7) << 4) | (did & 15);
                int kb = (did >> 4) & 7;
                const float* srcA = X + (size_t)(rowBase + row) * DF + k0 + kb * 8;
                const float* srcB = X + (size_t)(colBase + row) * DF + k0 + kb * 8;
                float4 a0 = *(const float4*)srcA;
                float4 a1 = *(const float4*)(srcA + 4);
                float4 e0 = *(const float4*)srcB;
                float4 e1 = *(const float4*)(srcB + 4);
                ushort8v va, vb;
                va[0] = f2bf(a0.x); va[1] = f2bf(a0.y); va[2] = f2bf(a0.z); va[3] = f2bf(a0.w);
                va[4] = f2bf(a1.x); va[5] = f2bf(a1.y); va[6] = f2bf(a1.z); va[7] = f2bf(a1.w);
                vb[0] = f2bf(e0.x); vb[1] = f2bf(e0.y); vb[2] = f2bf(e0.z); vb[3] = f2bf(e0.w);
                vb[4] = f2bf(e1.x); vb[5] = f2bf(e1.y); vb[6] = f2bf(e1.z); vb[7] = f2bf(e1.w);
                *((ushort8v*)(smem + (did << 4))) = va;
                *((ushort8v*)(smem + 16384 + (did << 4))) = vb;
            }
        }
        __syncthreads();
#pragma unroll
        for (int kk = 0; kk < 2; ++kk) {
            short8v a[4], b[4];
#pragma unroll
            for (int m = 0; m < 4; ++m)
                a[m] = *((const short8v*)(smem + (((wy * 4 + m) * 2 + kk) << 10) + (lane << 4)));
#pragma unroll
            for (int n = 0; n < 4; ++n)
                b[n] = *((const short8v*)(smem + 16384 + (((wx * 4 + n) * 2 + kk) << 10) + (lane << 4)));
#pragma unroll
            for (int m = 0; m < 4; ++m)
#pragma unroll
                for (int n = 0; n < 4; ++n)
                    acc4[m][n] = __builtin_amdgcn_mfma_f32_16x16x32_bf16(a[m], b[n], acc4[m][n], 0, 0, 0);
        }
    }
    __syncthreads();

    // overlay chord table onto staging LDS (32 KB exactly)
    float4* ft4 = (float4*)smem;
    for (int i = tid; i < 2048; i += 256) ft4[i] = ((const float4*)ftab_g)[i];
    __syncthreads();
    const float2* ftab = (const float2*)smem;
    float d0v = hdr[0], rmaxv = hdr[1], invw = hdr[2], Stot = hdr[3];
    bool diag = (by == bx);

    float local = 0.f;
    int g = lane >> 4;
    int cl = lane & 15;
#pragma unroll
    for (int m = 0; m < 4; ++m) {
#pragma unroll
        for (int n = 0; n < 4; ++n) {
            floatx4 v = acc4[m][n];
            int gcl = wx * 64 + n * 16 + cl;
            float x2cv = x2c[gcl];
#pragma unroll
            for (int r = 0; r < 4; ++r) {
                int grl = wy * 64 + m * 16 + g * 4 + r;
                if (diag && grl == gcl) continue;
                float d = fmaxf(x2r[grl] + x2cv - 2.f * v[r], 0.f);
                if (d >= rmaxv) continue;
                if (d < d0v) {
                    local += fmaf(-d, (float)N, Stot);
                } else {
                    float tpos = (d - d0v) * invw;
                    int b = min((int)tpos, NBINS2 - 1);
                    float frac = tpos - (float)b;
                    float2 ab = ftab[b];
                    local += fmaf(frac, ab.y, ab.x);
                }
            }
        }
    }
    red[tid] = local;
    __syncthreads();
    for (int s2 = 128; s2 > 0; s2 >>= 1) {
        if (tid < s2) red[tid] += red[tid + s2];
        __syncthreads();
    }
    if (tid == 0) {
        float wt = diag ? 1.f : 2.f;
        atomicAdd(&accd[1], (double)(wt * red[0]));
    }
}

// ---------------- finalize ----------------
__global__ void finalize_kernel(const double* __restrict__ accd, float* __restrict__ out) {
    out[0] = (float)((accd[0] + accd[1] - accd[2]) / (double)N);
}

extern "C" void kernel_launch(void* const* d_in, const int* in_sizes, int n_in,
                              void* d_out, int out_size, void* d_ws, size_t ws_size,
                              hipStream_t stream) {
    const float* X = (const float*)d_in[0];
    const int* labels = (const int*)d_in[1];
    float* out = (float*)d_out;

    char* w = (char*)d_ws;
    double* accd   = (double*)w;                        // 64 B
    float* x2      = (float*)(w + 64);                  // 16 KB
    float* radii   = (float*)(w + 64 + 16384);          // 16 KB
    float* targetd = (float*)(w + 64 + 32768);          // 48 KB
    int* cnt       = (int*)(w + 64 + 81920);            // 256 B
    int* members   = (int*)(w + 64 + 82176);            // 64 KB
    float* hdr     = (float*)(w + 64 + 147712);         // 64 B
    float2* ftab_g = (float2*)(w + 64 + 147776);        // 32 KB
    __hip_bfloat16* Xb = (__hip_bfloat16*)(w + 64 + 180544); // 2 MB
    size_t need_xb = 64 + 180544 + (size_t)N * DF * 2;
    bool useXb = ws_size >= need_xb;

    hipLaunchKernelGGL(x2_kernel, dim3(N / 4), dim3(256), 0, stream, X, x2);
    hipLaunchKernelGGL(bucket_kernel, dim3(1), dim3(1024), 0, stream, labels, cnt, members, accd);
    if (useXb)
        hipLaunchKernelGGL(cvt_kernel, dim3(N * DF / 1024), dim3(256), 0, stream, X, Xb);
    hipLaunchKernelGGL(knn_kernel, dim3(N), dim3(64), 0, stream,
                       X, labels, x2, cnt, members, radii, targetd, accd);
    hipLaunchKernelGGL(sort_scan_kernel, dim3(1), dim3(1024), 0, stream,
                       radii, targetd, ftab_g, hdr, accd);
    if (useXb)
        hipLaunchKernelGGL(push_gemm_kernel<1>, dim3(528), dim3(256), 0, stream,
                           X, Xb, x2, ftab_g, hdr, accd);
    else
        hipLaunchKernelGGL(push_gemm_kernel<0>, dim3(528), dim3(256), 0, stream,
                           X, Xb, x2, ftab_g, hdr, accd);
    hipLaunchKernelGGL(finalize_kernel, dim3(1), dim3(1), 0, stream, accd, out);
}